// Round 1
// baseline (465.838 us; speedup 1.0000x reference)
//
#include <hip/hip_runtime.h>
#include <hip/hip_bf16.h>

// ---------- types ----------
typedef __attribute__((ext_vector_type(8))) short s16x8;   // 8 bf16 (4 VGPR)
typedef __attribute__((ext_vector_type(4))) short s16x4;   // 4 bf16
typedef __attribute__((ext_vector_type(4))) float f32x4;

#define MFMA16(a, b, c) __builtin_amdgcn_mfma_f32_16x16x32_bf16(a, b, c, 0, 0, 0)

__device__ __forceinline__ short f2bf(float f) {
  unsigned int x = __builtin_bit_cast(unsigned int, f);
  x += 0x7fffu + ((x >> 16) & 1u);   // RNE; inputs always finite here
  return (short)(x >> 16);
}

// permuted LDS column so a lane's 8 fragment elements are contiguous:
// frag elem j (lane group g): j<4 -> k=4g+j ; j>=4 -> k=16+4g+(j-4)
// c(k) = gg*8 + b*4 + j  for k = b*16 + gg*4 + j
__device__ __forceinline__ int cperm(int k) {
  return ((k & 12) << 1) | ((k >> 4) << 2) | (k & 3);
}

#define LDT 40   // padded LDS row length (elements); rows 80B -> b128 reads conflict-free

// ---------- fp32 -> bf16 convert ----------
__global__ void cvt_f32_bf16(const float* __restrict__ in, short* __restrict__ out, int n) {
  int idx = blockIdx.x * blockDim.x + threadIdx.x;
  int stride = gridDim.x * blockDim.x;
  for (int i = idx * 4; i < n; i += stride * 4) {
    float4 v = *(const float4*)(in + i);
    s16x4 o;
    o[0] = f2bf(v.x); o[1] = f2bf(v.y); o[2] = f2bf(v.z); o[3] = f2bf(v.w);
    *(s16x4*)(out + i) = o;
  }
}

// ---------- GEMM1: qkv = Xb @ Wqkv + b, scatter to Q/K/V [B,N,S,H] bf16 ----------
// X: [8192][1024] bf16, W: [1024][3072] bf16, 128x128 tile, BK=32, 4 waves.
__global__ __launch_bounds__(256) void gemm_qkv(
    const short* __restrict__ X, const short* __restrict__ W,
    const float* __restrict__ bias,
    short* __restrict__ Qo, short* __restrict__ Ko, short* __restrict__ Vo) {
  const int N = 3072, Kd = 1024;
  __shared__ short As[128 * LDT];
  __shared__ short Bs[128 * LDT];
  int t = threadIdx.x;
  int nTN = N / 128;
  int m0 = (blockIdx.x / nTN) * 128;
  int n0 = (blockIdx.x % nTN) * 128;
  int lane = t & 63, w = t >> 6;
  int wr = (w >> 1) * 64, wc = (w & 1) * 64;
  int r = lane & 15, g = lane >> 4;

  int ar = t >> 1;             // A row 0..127
  int ak = (t & 1) << 4;       // k half 0/16
  int bk = t & 31;             // B k row
  int bc = (t >> 5) << 4;      // B col base (16 cols per thread)
  int cbk = cperm(bk);

  f32x4 acc[4][4];
  const f32x4 z4 = {0.f, 0.f, 0.f, 0.f};
#pragma unroll
  for (int i = 0; i < 4; ++i)
#pragma unroll
    for (int j = 0; j < 4; ++j) acc[i][j] = z4;

  for (int kt = 0; kt < Kd; kt += 32) {
    if (kt) __syncthreads();
    // stage A (rows of X)
    const short* xr = X + (size_t)(m0 + ar) * Kd + kt + ak;
    s16x8 va0 = *(const s16x8*)(xr);
    s16x8 va1 = *(const s16x8*)(xr + 8);
    short* Ad = &As[ar * LDT];
    *(s16x4*)(Ad + cperm(ak))      = __builtin_shufflevector(va0, va0, 0, 1, 2, 3);
    *(s16x4*)(Ad + cperm(ak + 4))  = __builtin_shufflevector(va0, va0, 4, 5, 6, 7);
    *(s16x4*)(Ad + cperm(ak + 8))  = __builtin_shufflevector(va1, va1, 0, 1, 2, 3);
    *(s16x4*)(Ad + cperm(ak + 12)) = __builtin_shufflevector(va1, va1, 4, 5, 6, 7);
    // stage B transposed (col-major in LDS)
    const short* wrp = W + (size_t)(kt + bk) * N + n0 + bc;
    s16x8 vb0 = *(const s16x8*)(wrp);
    s16x8 vb1 = *(const s16x8*)(wrp + 8);
#pragma unroll
    for (int i = 0; i < 8; ++i) Bs[(bc + i) * LDT + cbk] = vb0[i];
#pragma unroll
    for (int i = 0; i < 8; ++i) Bs[(bc + 8 + i) * LDT + cbk] = vb1[i];
    __syncthreads();

    s16x8 af[4], bfr[4];
#pragma unroll
    for (int mi = 0; mi < 4; ++mi)
      af[mi] = *(const s16x8*)(&As[(wr + mi * 16 + r) * LDT + g * 8]);
#pragma unroll
    for (int ni = 0; ni < 4; ++ni)
      bfr[ni] = *(const s16x8*)(&Bs[(wc + ni * 16 + r) * LDT + g * 8]);
#pragma unroll
    for (int mi = 0; mi < 4; ++mi)
#pragma unroll
      for (int ni = 0; ni < 4; ++ni)
        acc[mi][ni] = MFMA16(af[mi], bfr[ni], acc[mi][ni]);
  }

  // epilogue: bias + scatter to [B=4,N=16,S=2048,H=64]
#pragma unroll
  for (int ni = 0; ni < 4; ++ni) {
    int col = n0 + wc + ni * 16 + r;
    float bv = bias[col];
    int which = col >> 10;
    int rem = col & 1023;
    int head = rem >> 6, h = rem & 63;
    short* dst = (which == 0) ? Qo : (which == 1) ? Ko : Vo;
#pragma unroll
    for (int mi = 0; mi < 4; ++mi)
#pragma unroll
      for (int e = 0; e < 4; ++e) {
        int row = m0 + wr + mi * 16 + g * 4 + e;
        int b = row >> 11, s = row & 2047;
        dst[((size_t)(b * 16 + head) * 2048 + s) * 64 + h] = f2bf(acc[mi][ni][e] + bv);
      }
  }
}

// ---------- GEMM2: out = AttnOut @ Wout + b, fp32 out ----------
__global__ __launch_bounds__(256) void gemm_out(
    const short* __restrict__ X, const short* __restrict__ W,
    const float* __restrict__ bias, float* __restrict__ Out) {
  const int N = 1024, Kd = 1024;
  __shared__ short As[128 * LDT];
  __shared__ short Bs[128 * LDT];
  int t = threadIdx.x;
  int nTN = N / 128;
  int m0 = (blockIdx.x / nTN) * 128;
  int n0 = (blockIdx.x % nTN) * 128;
  int lane = t & 63, w = t >> 6;
  int wr = (w >> 1) * 64, wc = (w & 1) * 64;
  int r = lane & 15, g = lane >> 4;
  int ar = t >> 1, ak = (t & 1) << 4;
  int bk = t & 31, bc = (t >> 5) << 4;
  int cbk = cperm(bk);

  f32x4 acc[4][4];
  const f32x4 z4 = {0.f, 0.f, 0.f, 0.f};
#pragma unroll
  for (int i = 0; i < 4; ++i)
#pragma unroll
    for (int j = 0; j < 4; ++j) acc[i][j] = z4;

  for (int kt = 0; kt < Kd; kt += 32) {
    if (kt) __syncthreads();
    const short* xr = X + (size_t)(m0 + ar) * Kd + kt + ak;
    s16x8 va0 = *(const s16x8*)(xr);
    s16x8 va1 = *(const s16x8*)(xr + 8);
    short* Ad = &As[ar * LDT];
    *(s16x4*)(Ad + cperm(ak))      = __builtin_shufflevector(va0, va0, 0, 1, 2, 3);
    *(s16x4*)(Ad + cperm(ak + 4))  = __builtin_shufflevector(va0, va0, 4, 5, 6, 7);
    *(s16x4*)(Ad + cperm(ak + 8))  = __builtin_shufflevector(va1, va1, 0, 1, 2, 3);
    *(s16x4*)(Ad + cperm(ak + 12)) = __builtin_shufflevector(va1, va1, 4, 5, 6, 7);
    const short* wrp = W + (size_t)(kt + bk) * N + n0 + bc;
    s16x8 vb0 = *(const s16x8*)(wrp);
    s16x8 vb1 = *(const s16x8*)(wrp + 8);
#pragma unroll
    for (int i = 0; i < 8; ++i) Bs[(bc + i) * LDT + cbk] = vb0[i];
#pragma unroll
    for (int i = 0; i < 8; ++i) Bs[(bc + 8 + i) * LDT + cbk] = vb1[i];
    __syncthreads();

    s16x8 af[4], bfr[4];
#pragma unroll
    for (int mi = 0; mi < 4; ++mi)
      af[mi] = *(const s16x8*)(&As[(wr + mi * 16 + r) * LDT + g * 8]);
#pragma unroll
    for (int ni = 0; ni < 4; ++ni)
      bfr[ni] = *(const s16x8*)(&Bs[(wc + ni * 16 + r) * LDT + g * 8]);
#pragma unroll
    for (int mi = 0; mi < 4; ++mi)
#pragma unroll
      for (int ni = 0; ni < 4; ++ni)
        acc[mi][ni] = MFMA16(af[mi], bfr[ni], acc[mi][ni]);
  }

#pragma unroll
  for (int ni = 0; ni < 4; ++ni) {
    int col = n0 + wc + ni * 16 + r;
    float bv = bias[col];
#pragma unroll
    for (int mi = 0; mi < 4; ++mi)
#pragma unroll
      for (int e = 0; e < 4; ++e) {
        int row = m0 + wr + mi * 16 + g * 4 + e;
        Out[(size_t)row * N + col] = acc[mi][ni][e] + bv;
      }
  }
}

// ---------- causal flash attention ----------
// Q/K/V: [B*N][S][64] bf16. Block: one (b,n) x 128 q-rows; 4 waves x 32 q-rows.
// Swapped QK^T: st = mfma(K_frag, Q_frag) -> S^T; softmax stats per q = lane&15.
__global__ __launch_bounds__(256) void attn(
    const short* __restrict__ Qb, const short* __restrict__ Kb,
    const short* __restrict__ Vb, short* __restrict__ Ob) {
  const int S = 2048, H = 64;
  const int nqt = S / 128;
  int bn = blockIdx.x / nqt;
  int qt = blockIdx.x % nqt;
  int batch = bn >> 4, head = bn & 15;
  int q0 = qt * 128;
  int t = threadIdx.x, lane = t & 63, w = t >> 6;
  int r = lane & 15, g = lane >> 4;
  int qw = q0 + w * 32;

  const short* Qh = Qb + (size_t)bn * S * H;
  const short* Kh = Kb + (size_t)bn * S * H;
  const short* Vh = Vb + (size_t)bn * S * H;

  __shared__ short Vs[64 * LDT];

  // hoist Q fragments: B-operand [k=h][col=q]; qf[n][ks]
  s16x8 qf[2][2];
#pragma unroll
  for (int n = 0; n < 2; ++n)
#pragma unroll
    for (int ks = 0; ks < 2; ++ks) {
      const short* qr = Qh + (size_t)(qw + n * 16 + r) * H + ks * 32 + g * 4;
      s16x4 lo = *(const s16x4*)(qr);
      s16x4 hi = *(const s16x4*)(qr + 16);
      qf[n][ks] = __builtin_shufflevector(lo, hi, 0, 1, 2, 3, 4, 5, 6, 7);
    }

  f32x4 o[2][4];
  const f32x4 z4 = {0.f, 0.f, 0.f, 0.f};
#pragma unroll
  for (int n = 0; n < 2; ++n)
#pragma unroll
    for (int hb = 0; hb < 4; ++hb) o[n][hb] = z4;
  float mrun[2] = {-__builtin_inff(), -__builtin_inff()};
  float lrun[2] = {0.f, 0.f};

  int ntiles = q0 / 32 + 4;
  int mytile = q0 / 32 + w;   // last kv-tile this wave needs
  int vk = t & 31, vh = (t >> 5) << 3;
  int cvk = cperm(vk);

  for (int tkv = 0; tkv < ntiles; ++tkv) {
    int kv0 = tkv * 32;
    if (tkv) __syncthreads();
    // stage V tile [32][64] -> VT_lds[h][c(kv)]
    s16x8 vv = *(const s16x8*)(Vh + (size_t)(kv0 + vk) * H + vh);
#pragma unroll
    for (int i = 0; i < 8; ++i) Vs[(vh + i) * LDT + cvk] = vv[i];
    __syncthreads();
    if (tkv > mytile) continue;

    // K fragments (A-operand rows = kv)
    s16x8 kf[2][2];
#pragma unroll
    for (int mp = 0; mp < 2; ++mp)
#pragma unroll
      for (int ks = 0; ks < 2; ++ks) {
        const short* kr = Kh + (size_t)(kv0 + mp * 16 + r) * H + ks * 32 + g * 4;
        s16x4 lo = *(const s16x4*)(kr);
        s16x4 hi = *(const s16x4*)(kr + 16);
        kf[mp][ks] = __builtin_shufflevector(lo, hi, 0, 1, 2, 3, 4, 5, 6, 7);
      }

    f32x4 st[2][2];
#pragma unroll
    for (int mp = 0; mp < 2; ++mp)
#pragma unroll
      for (int n = 0; n < 2; ++n) st[mp][n] = z4;
#pragma unroll
    for (int mp = 0; mp < 2; ++mp)
#pragma unroll
      for (int n = 0; n < 2; ++n)
#pragma unroll
        for (int ks = 0; ks < 2; ++ks)
          st[mp][n] = MFMA16(kf[mp][ks], qf[n][ks], st[mp][n]);

    bool need_mask = (tkv == mytile);
    float p[2][2][4];
    float rmax[2] = {-__builtin_inff(), -__builtin_inff()};
#pragma unroll
    for (int n = 0; n < 2; ++n)
#pragma unroll
      for (int mp = 0; mp < 2; ++mp)
#pragma unroll
        for (int e = 0; e < 4; ++e) {
          float v = st[mp][n][e] * 0.125f;   // 1/sqrt(64)
          if (need_mask) {
            int kv = kv0 + mp * 16 + g * 4 + e;
            int q = qw + n * 16 + r;
            if (kv > q) v = -__builtin_inff();
          }
          p[mp][n][e] = v;
          rmax[n] = fmaxf(rmax[n], v);
        }
#pragma unroll
    for (int n = 0; n < 2; ++n) {
      rmax[n] = fmaxf(rmax[n], __shfl_xor(rmax[n], 16));
      rmax[n] = fmaxf(rmax[n], __shfl_xor(rmax[n], 32));
    }
    float mnew[2], sc[2], rsum[2];
#pragma unroll
    for (int n = 0; n < 2; ++n) {
      mnew[n] = fmaxf(mrun[n], rmax[n]);
      sc[n] = __expf(mrun[n] - mnew[n]);
      rsum[n] = 0.f;
    }
#pragma unroll
    for (int n = 0; n < 2; ++n)
#pragma unroll
      for (int mp = 0; mp < 2; ++mp)
#pragma unroll
        for (int e = 0; e < 4; ++e) {
          float ev = __expf(p[mp][n][e] - mnew[n]);
          p[mp][n][e] = ev;
          rsum[n] += ev;
        }
#pragma unroll
    for (int n = 0; n < 2; ++n) {
      rsum[n] += __shfl_xor(rsum[n], 16);
      rsum[n] += __shfl_xor(rsum[n], 32);
      lrun[n] = lrun[n] * sc[n] + rsum[n];
      mrun[n] = mnew[n];
    }
    // rescale O: O rows are q' = 4g+e, scale lives at lane with (l&15)==q'
#pragma unroll
    for (int n = 0; n < 2; ++n)
#pragma unroll
      for (int e = 0; e < 4; ++e) {
        float bs = __shfl(sc[n], (lane & 48) + g * 4 + e);
#pragma unroll
        for (int hb = 0; hb < 4; ++hb) o[n][hb][e] *= bs;
      }
    // P -> bf16 A-fragments (pure-local thanks to swapped layout)
    s16x8 pa[2];
#pragma unroll
    for (int n = 0; n < 2; ++n) {
      s16x8 tmp = {f2bf(p[0][n][0]), f2bf(p[0][n][1]), f2bf(p[0][n][2]), f2bf(p[0][n][3]),
                   f2bf(p[1][n][0]), f2bf(p[1][n][1]), f2bf(p[1][n][2]), f2bf(p[1][n][3])};
      pa[n] = tmp;
    }
    // PV
#pragma unroll
    for (int hb = 0; hb < 4; ++hb) {
      s16x8 vf = *(const s16x8*)(&Vs[(hb * 16 + r) * LDT + g * 8]);
#pragma unroll
      for (int n = 0; n < 2; ++n) o[n][hb] = MFMA16(pa[n], vf, o[n][hb]);
    }
  }

  // epilogue: O /= l, write [B,S,N*H] bf16
#pragma unroll
  for (int n = 0; n < 2; ++n) {
    float il = 1.0f / lrun[n];
#pragma unroll
    for (int e = 0; e < 4; ++e) {
      float bv = __shfl(il, (lane & 48) + g * 4 + e);
      int s = qw + n * 16 + g * 4 + e;
#pragma unroll
      for (int hb = 0; hb < 4; ++hb) {
        int c = head * 64 + hb * 16 + r;
        Ob[(size_t)(batch * 2048 + s) * 1024 + c] = f2bf(o[n][hb][e] * bv);
      }
    }
  }
}

// ---------- launch ----------
extern "C" void kernel_launch(void* const* d_in, const int* in_sizes, int n_in,
                              void* d_out, int out_size, void* d_ws, size_t ws_size,
                              hipStream_t stream) {
  const float* x    = (const float*)d_in[0];   // [4,2048,1024]
  const float* Wqkv = (const float*)d_in[1];   // [1024,3072]
  const float* bqkv = (const float*)d_in[2];   // [3072]
  const float* Wout = (const float*)d_in[3];   // [1024,1024]
  const float* bout = (const float*)d_in[4];   // [1024]
  float* out = (float*)d_out;

  char* ws = (char*)d_ws;
  short* Xb    = (short*)(ws);                          // 16 MB (reused as attn-out)
  short* Wqkvb = (short*)(ws + ((size_t)16 << 20));     // 6 MB
  short* Woutb = (short*)(ws + ((size_t)22 << 20));     // 2 MB
  short* Qb    = (short*)(ws + ((size_t)24 << 20));     // 16 MB
  short* Kb    = (short*)(ws + ((size_t)40 << 20));     // 16 MB
  short* Vb    = (short*)(ws + ((size_t)56 << 20));     // 16 MB  (total 72 MB)

  cvt_f32_bf16<<<2048, 256, 0, stream>>>(x, Xb, 4 * 2048 * 1024);
  cvt_f32_bf16<<<1024, 256, 0, stream>>>(Wqkv, Wqkvb, 1024 * 3072);
  cvt_f32_bf16<<<512, 256, 0, stream>>>(Wout, Woutb, 1024 * 1024);

  gemm_qkv<<<64 * 24, 256, 0, stream>>>(Xb, Wqkvb, bqkv, Qb, Kb, Vb);
  attn<<<64 * 16, 256, 0, stream>>>(Qb, Kb, Vb, Xb);
  gemm_out<<<64 * 8, 256, 0, stream>>>(Xb, Woutb, bout, out);
}

// Round 2
// 281.445 us; speedup vs baseline: 1.6552x; 1.6552x over previous
//
#include <hip/hip_runtime.h>
#include <hip/hip_bf16.h>

// ---------- types ----------
typedef __attribute__((ext_vector_type(8))) short s16x8;   // 8 bf16 (4 VGPR)
typedef __attribute__((ext_vector_type(4))) short s16x4;   // 4 bf16
typedef __attribute__((ext_vector_type(4))) float f32x4;

#define MFMA16(a, b, c) __builtin_amdgcn_mfma_f32_16x16x32_bf16(a, b, c, 0, 0, 0)

__device__ __forceinline__ short f2bf(float f) {
  unsigned int x = __builtin_bit_cast(unsigned int, f);
  x += 0x7fffu + ((x >> 16) & 1u);   // RNE; inputs always finite here
  return (short)(x >> 16);
}

// permuted LDS column so a lane's 8 fragment elements are contiguous:
// frag elem j (lane group g): j<4 -> k=4g+j ; j>=4 -> k=16+4g+(j-4)
__device__ __forceinline__ int cperm(int k) {
  return ((k & 12) << 1) | ((k >> 4) << 2) | (k & 3);
}

#define LDT 40   // padded LDS row length for GEMM tiles

// ---------- fp32 -> bf16 convert ----------
__global__ void cvt_f32_bf16(const float* __restrict__ in, short* __restrict__ out, int n) {
  int idx = blockIdx.x * blockDim.x + threadIdx.x;
  int stride = gridDim.x * blockDim.x;
  for (int i = idx * 4; i < n; i += stride * 4) {
    float4 v = *(const float4*)(in + i);
    s16x4 o;
    o[0] = f2bf(v.x); o[1] = f2bf(v.y); o[2] = f2bf(v.z); o[3] = f2bf(v.w);
    *(s16x4*)(out + i) = o;
  }
}

// ---------- GEMM1: qkv = Xb @ Wqkv + b, scatter to Q/K/V [B,N,S,H] bf16 ----------
__global__ __launch_bounds__(256) void gemm_qkv(
    const short* __restrict__ X, const short* __restrict__ W,
    const float* __restrict__ bias,
    short* __restrict__ Qo, short* __restrict__ Ko, short* __restrict__ Vo) {
  const int N = 3072, Kd = 1024;
  __shared__ short As[128 * LDT];
  __shared__ short Bs[128 * LDT];
  int t = threadIdx.x;
  int nTN = N / 128;
  int m0 = (blockIdx.x / nTN) * 128;
  int n0 = (blockIdx.x % nTN) * 128;
  int lane = t & 63, w = t >> 6;
  int wr = (w >> 1) * 64, wc = (w & 1) * 64;
  int r = lane & 15, g = lane >> 4;

  int ar = t >> 1;
  int ak = (t & 1) << 4;
  int bk = t & 31;
  int bc = (t >> 5) << 4;
  int cbk = cperm(bk);

  f32x4 acc[4][4];
  const f32x4 z4 = {0.f, 0.f, 0.f, 0.f};
#pragma unroll
  for (int i = 0; i < 4; ++i)
#pragma unroll
    for (int j = 0; j < 4; ++j) acc[i][j] = z4;

  for (int kt = 0; kt < Kd; kt += 32) {
    if (kt) __syncthreads();
    const short* xr = X + (size_t)(m0 + ar) * Kd + kt + ak;
    s16x8 va0 = *(const s16x8*)(xr);
    s16x8 va1 = *(const s16x8*)(xr + 8);
    short* Ad = &As[ar * LDT];
    *(s16x4*)(Ad + cperm(ak))      = __builtin_shufflevector(va0, va0, 0, 1, 2, 3);
    *(s16x4*)(Ad + cperm(ak + 4))  = __builtin_shufflevector(va0, va0, 4, 5, 6, 7);
    *(s16x4*)(Ad + cperm(ak + 8))  = __builtin_shufflevector(va1, va1, 0, 1, 2, 3);
    *(s16x4*)(Ad + cperm(ak + 12)) = __builtin_shufflevector(va1, va1, 4, 5, 6, 7);
    const short* wrp = W + (size_t)(kt + bk) * N + n0 + bc;
    s16x8 vb0 = *(const s16x8*)(wrp);
    s16x8 vb1 = *(const s16x8*)(wrp + 8);
#pragma unroll
    for (int i = 0; i < 8; ++i) Bs[(bc + i) * LDT + cbk] = vb0[i];
#pragma unroll
    for (int i = 0; i < 8; ++i) Bs[(bc + 8 + i) * LDT + cbk] = vb1[i];
    __syncthreads();

    s16x8 af[4], bfr[4];
#pragma unroll
    for (int mi = 0; mi < 4; ++mi)
      af[mi] = *(const s16x8*)(&As[(wr + mi * 16 + r) * LDT + g * 8]);
#pragma unroll
    for (int ni = 0; ni < 4; ++ni)
      bfr[ni] = *(const s16x8*)(&Bs[(wc + ni * 16 + r) * LDT + g * 8]);
#pragma unroll
    for (int mi = 0; mi < 4; ++mi)
#pragma unroll
      for (int ni = 0; ni < 4; ++ni)
        acc[mi][ni] = MFMA16(af[mi], bfr[ni], acc[mi][ni]);
  }

#pragma unroll
  for (int ni = 0; ni < 4; ++ni) {
    int col = n0 + wc + ni * 16 + r;
    float bv = bias[col];
    int which = col >> 10;
    int rem = col & 1023;
    int head = rem >> 6, h = rem & 63;
    short* dst = (which == 0) ? Qo : (which == 1) ? Ko : Vo;
#pragma unroll
    for (int mi = 0; mi < 4; ++mi)
#pragma unroll
      for (int e = 0; e < 4; ++e) {
        int row = m0 + wr + mi * 16 + g * 4 + e;
        int b = row >> 11, s = row & 2047;
        dst[((size_t)(b * 16 + head) * 2048 + s) * 64 + h] = f2bf(acc[mi][ni][e] + bv);
      }
  }
}

// ---------- GEMM2: out = AttnOut @ Wout + b, fp32 out ----------
__global__ __launch_bounds__(256) void gemm_out(
    const short* __restrict__ X, const short* __restrict__ W,
    const float* __restrict__ bias, float* __restrict__ Out) {
  const int N = 1024, Kd = 1024;
  __shared__ short As[128 * LDT];
  __shared__ short Bs[128 * LDT];
  int t = threadIdx.x;
  int nTN = N / 128;
  int m0 = (blockIdx.x / nTN) * 128;
  int n0 = (blockIdx.x % nTN) * 128;
  int lane = t & 63, w = t >> 6;
  int wr = (w >> 1) * 64, wc = (w & 1) * 64;
  int r = lane & 15, g = lane >> 4;
  int ar = t >> 1, ak = (t & 1) << 4;
  int bk = t & 31, bc = (t >> 5) << 4;
  int cbk = cperm(bk);

  f32x4 acc[4][4];
  const f32x4 z4 = {0.f, 0.f, 0.f, 0.f};
#pragma unroll
  for (int i = 0; i < 4; ++i)
#pragma unroll
    for (int j = 0; j < 4; ++j) acc[i][j] = z4;

  for (int kt = 0; kt < Kd; kt += 32) {
    if (kt) __syncthreads();
    const short* xr = X + (size_t)(m0 + ar) * Kd + kt + ak;
    s16x8 va0 = *(const s16x8*)(xr);
    s16x8 va1 = *(const s16x8*)(xr + 8);
    short* Ad = &As[ar * LDT];
    *(s16x4*)(Ad + cperm(ak))      = __builtin_shufflevector(va0, va0, 0, 1, 2, 3);
    *(s16x4*)(Ad + cperm(ak + 4))  = __builtin_shufflevector(va0, va0, 4, 5, 6, 7);
    *(s16x4*)(Ad + cperm(ak + 8))  = __builtin_shufflevector(va1, va1, 0, 1, 2, 3);
    *(s16x4*)(Ad + cperm(ak + 12)) = __builtin_shufflevector(va1, va1, 4, 5, 6, 7);
    const short* wrp = W + (size_t)(kt + bk) * N + n0 + bc;
    s16x8 vb0 = *(const s16x8*)(wrp);
    s16x8 vb1 = *(const s16x8*)(wrp + 8);
#pragma unroll
    for (int i = 0; i < 8; ++i) Bs[(bc + i) * LDT + cbk] = vb0[i];
#pragma unroll
    for (int i = 0; i < 8; ++i) Bs[(bc + 8 + i) * LDT + cbk] = vb1[i];
    __syncthreads();

    s16x8 af[4], bfr[4];
#pragma unroll
    for (int mi = 0; mi < 4; ++mi)
      af[mi] = *(const s16x8*)(&As[(wr + mi * 16 + r) * LDT + g * 8]);
#pragma unroll
    for (int ni = 0; ni < 4; ++ni)
      bfr[ni] = *(const s16x8*)(&Bs[(wc + ni * 16 + r) * LDT + g * 8]);
#pragma unroll
    for (int mi = 0; mi < 4; ++mi)
#pragma unroll
      for (int ni = 0; ni < 4; ++ni)
        acc[mi][ni] = MFMA16(af[mi], bfr[ni], acc[mi][ni]);
  }

#pragma unroll
  for (int ni = 0; ni < 4; ++ni) {
    int col = n0 + wc + ni * 16 + r;
    float bv = bias[col];
#pragma unroll
    for (int mi = 0; mi < 4; ++mi)
#pragma unroll
      for (int e = 0; e < 4; ++e) {
        int row = m0 + wr + mi * 16 + g * 4 + e;
        Out[(size_t)row * N + col] = acc[mi][ni][e] + bv;
      }
  }
}

// ---------- causal flash attention (KV tile = 64, defer-rescale, balanced) ----------
// Q/K/V: [B*N][S][64] bf16. Block: one (b,n) x 128 q-rows; 4 waves x 32 q-rows.
// Swapped QK^T: st = mfma(K_frag, Q_frag) -> S^T; softmax stats per q = lane&15.
#define LDTV 72  // V LDS row stride (64 cols + pad), 144B rows, b128 reads 2-way (free)
__global__ __launch_bounds__(256) void attn(
    const short* __restrict__ Qb, const short* __restrict__ Kb,
    const short* __restrict__ Vb, short* __restrict__ Ob) {
  const int S = 2048, H = 64;
  int bid = blockIdx.x;
  int qt = 15 - (bid >> 6);          // heavy q-tiles dispatch first
  int bn = bid & 63;
  int batch = bn >> 4, head = bn & 15;
  int q0 = qt * 128;
  int t = threadIdx.x, lane = t & 63, w = t >> 6;
  int r = lane & 15, g = lane >> 4;
  int qw = q0 + w * 32;

  const short* Qh = Qb + (size_t)bn * S * H;
  const short* Kh = Kb + (size_t)bn * S * H;
  const short* Vh = Vb + (size_t)bn * S * H;

  __shared__ short Vs[64 * LDTV];

  // hoist Q fragments: B-operand [k=h][col=q]; qf[n][ks]
  s16x8 qf[2][2];
#pragma unroll
  for (int n = 0; n < 2; ++n)
#pragma unroll
    for (int ks = 0; ks < 2; ++ks) {
      const short* qr = Qh + (size_t)(qw + n * 16 + r) * H + ks * 32 + g * 4;
      s16x4 lo = *(const s16x4*)(qr);
      s16x4 hi = *(const s16x4*)(qr + 16);
      qf[n][ks] = __builtin_shufflevector(lo, hi, 0, 1, 2, 3, 4, 5, 6, 7);
    }

  f32x4 o[2][4];
  const f32x4 z4 = {0.f, 0.f, 0.f, 0.f};
#pragma unroll
  for (int n = 0; n < 2; ++n)
#pragma unroll
    for (int hb = 0; hb < 4; ++hb) o[n][hb] = z4;
  float mrun[2] = {-__builtin_inff(), -__builtin_inff()};
  float lrun[2] = {0.f, 0.f};

  int ntiles = q0 / 64 + 2;          // covers kv 0 .. q0+127

  // V staging coords: each thread owns one kv row (vr), 16 h cols (hbase)
  int vr = lane;                     // t & 63
  int hbase = w * 16;
  int vcol = ((vr >> 5) << 5) + cperm(vr & 31);

  // prefetch V tile 0
  s16x8 v0 = *(const s16x8*)(Vh + (size_t)vr * H + hbase);
  s16x8 v1 = *(const s16x8*)(Vh + (size_t)vr * H + hbase + 8);

  for (int tt = 0; tt < ntiles; ++tt) {
    int kv0 = tt * 64;
    if (tt) __syncthreads();         // prev tile compute done
    // scatter V(t) regs -> LDS transposed (cperm cols per 32-half)
#pragma unroll
    for (int i = 0; i < 8; ++i) Vs[(hbase + i) * LDTV + vcol] = v0[i];
#pragma unroll
    for (int i = 0; i < 8; ++i) Vs[(hbase + 8 + i) * LDTV + vcol] = v1[i];
    __syncthreads();
    // prefetch V(t+1) — latency hides under compute below
    if (tt + 1 < ntiles) {
      const short* vp = Vh + (size_t)((tt + 1) * 64 + vr) * H + hbase;
      v0 = *(const s16x8*)(vp);
      v1 = *(const s16x8*)(vp + 8);
    }
    if (kv0 > qw + 31) continue;     // fully masked for this wave

    int mpmax = (qw + 31 - kv0) >> 4; if (mpmax > 3) mpmax = 3;
    bool need_mask = (kv0 + 63 > qw);

    // hoist all K fragments (A-operand rows = kv)
    s16x8 kf[4][2];
#pragma unroll
    for (int mp = 0; mp < 4; ++mp) {
      if (mp <= mpmax) {
#pragma unroll
        for (int ks = 0; ks < 2; ++ks) {
          const short* kr = Kh + (size_t)(kv0 + mp * 16 + r) * H + ks * 32 + g * 4;
          s16x4 lo = *(const s16x4*)(kr);
          s16x4 hi = *(const s16x4*)(kr + 16);
          kf[mp][ks] = __builtin_shufflevector(lo, hi, 0, 1, 2, 3, 4, 5, 6, 7);
        }
      }
    }

    float p[4][2][4];
    float rmax[2] = {-__builtin_inff(), -__builtin_inff()};
#pragma unroll
    for (int mp = 0; mp < 4; ++mp) {
      if (mp <= mpmax) {
        f32x4 st[2] = {z4, z4};
#pragma unroll
        for (int n = 0; n < 2; ++n)
#pragma unroll
          for (int ks = 0; ks < 2; ++ks)
            st[n] = MFMA16(kf[mp][ks], qf[n][ks], st[n]);
#pragma unroll
        for (int n = 0; n < 2; ++n)
#pragma unroll
          for (int e = 0; e < 4; ++e) {
            float v = st[n][e] * 0.125f;     // 1/sqrt(64)
            if (need_mask) {
              int kv = kv0 + mp * 16 + g * 4 + e;
              int q = qw + n * 16 + r;
              if (kv > q) v = -__builtin_inff();
            }
            p[mp][n][e] = v;
            rmax[n] = fmaxf(rmax[n], v);
          }
      } else {
#pragma unroll
        for (int n = 0; n < 2; ++n)
#pragma unroll
          for (int e = 0; e < 4; ++e) p[mp][n][e] = 0.f;
      }
    }

#pragma unroll
    for (int n = 0; n < 2; ++n) {
      rmax[n] = fmaxf(rmax[n], __shfl_xor(rmax[n], 16));
      rmax[n] = fmaxf(rmax[n], __shfl_xor(rmax[n], 32));
    }

    // defer-rescale (T13, THR=8): only rescale when max grows materially
#pragma unroll
    for (int n = 0; n < 2; ++n) {
      if (!__all(rmax[n] - mrun[n] <= 8.0f)) {
        float mnew = fmaxf(mrun[n], rmax[n]);
        float sc = __expf(mrun[n] - mnew);
        lrun[n] *= sc;
        mrun[n] = mnew;
#pragma unroll
        for (int e = 0; e < 4; ++e) {
          float bs = __shfl(sc, (lane & 48) + g * 4 + e);
#pragma unroll
          for (int hb = 0; hb < 4; ++hb) o[n][hb][e] *= bs;
        }
      }
    }

    float rsum[2] = {0.f, 0.f};
#pragma unroll
    for (int mp = 0; mp < 4; ++mp) {
      if (mp <= mpmax) {
#pragma unroll
        for (int n = 0; n < 2; ++n)
#pragma unroll
          for (int e = 0; e < 4; ++e) {
            float ev = __expf(p[mp][n][e] - mrun[n]);
            p[mp][n][e] = ev;
            rsum[n] += ev;
          }
      }
    }
#pragma unroll
    for (int n = 0; n < 2; ++n) {
      rsum[n] += __shfl_xor(rsum[n], 16);
      rsum[n] += __shfl_xor(rsum[n], 32);
      lrun[n] += rsum[n];
    }

    // P -> bf16 A-fragments; pa[n][kvh] covers kv = kvh*32 .. +31
    int kvhmax = mpmax >> 1;
#pragma unroll
    for (int kvh = 0; kvh < 2; ++kvh) {
      if (kvh > kvhmax) break;
      s16x8 pa[2];
#pragma unroll
      for (int n = 0; n < 2; ++n) {
        s16x8 tmp = {f2bf(p[2 * kvh][n][0]),     f2bf(p[2 * kvh][n][1]),
                     f2bf(p[2 * kvh][n][2]),     f2bf(p[2 * kvh][n][3]),
                     f2bf(p[2 * kvh + 1][n][0]), f2bf(p[2 * kvh + 1][n][1]),
                     f2bf(p[2 * kvh + 1][n][2]), f2bf(p[2 * kvh + 1][n][3])};
        pa[n] = tmp;
      }
#pragma unroll
      for (int hb = 0; hb < 4; ++hb) {
        s16x8 vf = *(const s16x8*)(&Vs[(hb * 16 + r) * LDTV + kvh * 32 + g * 8]);
#pragma unroll
        for (int n = 0; n < 2; ++n) o[n][hb] = MFMA16(pa[n], vf, o[n][hb]);
      }
    }
  }

  // epilogue: O /= l, write [B,S,N*H] bf16
#pragma unroll
  for (int n = 0; n < 2; ++n) {
    float il = 1.0f / lrun[n];
#pragma unroll
    for (int e = 0; e < 4; ++e) {
      float bv = __shfl(il, (lane & 48) + g * 4 + e);
      int s = qw + n * 16 + g * 4 + e;
#pragma unroll
      for (int hb = 0; hb < 4; ++hb) {
        int c = head * 64 + hb * 16 + r;
        Ob[(size_t)(batch * 2048 + s) * 1024 + c] = f2bf(o[n][hb][e] * bv);
      }
    }
  }
}

// ---------- launch ----------
extern "C" void kernel_launch(void* const* d_in, const int* in_sizes, int n_in,
                              void* d_out, int out_size, void* d_ws, size_t ws_size,
                              hipStream_t stream) {
  const float* x    = (const float*)d_in[0];   // [4,2048,1024]
  const float* Wqkv = (const float*)d_in[1];   // [1024,3072]
  const float* bqkv = (const float*)d_in[2];   // [3072]
  const float* Wout = (const float*)d_in[3];   // [1024,1024]
  const float* bout = (const float*)d_in[4];   // [1024]
  float* out = (float*)d_out;

  char* ws = (char*)d_ws;
  short* Xb    = (short*)(ws);                          // 16 MB (reused as attn-out)
  short* Wqkvb = (short*)(ws + ((size_t)16 << 20));     // 6 MB
  short* Woutb = (short*)(ws + ((size_t)22 << 20));     // 2 MB
  short* Qb    = (short*)(ws + ((size_t)24 << 20));     // 16 MB
  short* Kb    = (short*)(ws + ((size_t)40 << 20));     // 16 MB
  short* Vb    = (short*)(ws + ((size_t)56 << 20));     // 16 MB  (total 72 MB)

  cvt_f32_bf16<<<2048, 256, 0, stream>>>(x, Xb, 4 * 2048 * 1024);
  cvt_f32_bf16<<<1024, 256, 0, stream>>>(Wqkv, 1024 * 3072 ? (short*)Wqkvb : Wqkvb, 1024 * 3072);
  cvt_f32_bf16<<<512, 256, 0, stream>>>(Wout, Woutb, 1024 * 1024);

  gemm_qkv<<<64 * 24, 256, 0, stream>>>(Xb, Wqkvb, bqkv, Qb, Kb, Vb);
  attn<<<64 * 16, 256, 0, stream>>>(Qb, Kb, Vb, Xb);
  gemm_out<<<64 * 8, 256, 0, stream>>>(Xb, Woutb, bout, out);
}